// Round 12
// baseline (356.863 us; speedup 1.0000x reference)
//
#include <hip/hip_runtime.h>
#include <hip/hip_bf16.h>
#include <hip/hip_fp16.h>

#define DEV __device__ __forceinline__

typedef __attribute__((ext_vector_type(8))) _Float16 h8;
typedef __attribute__((ext_vector_type(4))) float floatx4;

DEV float bf2f(unsigned short b) { return __uint_as_float(((unsigned)b) << 16); }

DEV void async_ld16(const void* g, void* l) {
  __builtin_amdgcn_global_load_lds(
      (const __attribute__((address_space(1))) unsigned int*)g,
      (__attribute__((address_space(3))) unsigned int*)l, 16, 0, 0);
}

// Runtime dtype probe (safety net): 1 if float tensors are bf16-packed, 0 if fp32.
DEV int detect_bf16(const void* x_mean) {
  const unsigned* w = (const unsigned*)x_mean;
  unsigned v = w[threadIdx.x & 63];
  unsigned ex = (v >> 7) & 0xFFu;
  int vote = (ex >= 100u && ex <= 144u) ? 1 : 0;
  unsigned long long b = __ballot(vote);
  return __popcll(b) >= 48 ? 1 : 0;
}

DEV float load_elem(const void* p, int isbf, size_t i) {
  return isbf ? bf2f(((const unsigned short*)p)[i]) : ((const float*)p)[i];
}

// Load 8 consecutive elements (fp32 or bf16) -> 8 fp16 into LDS.
DEV void stage8h(const void* src, int isbf, size_t idx, _Float16* dst) {
  h8 o;
  if (isbf) {
    const unsigned short* s = (const unsigned short*)src + idx;
#pragma unroll
    for (int j = 0; j < 8; ++j) o[j] = (_Float16)bf2f(s[j]);
  } else {
    const float* f = (const float*)src + idx;
    float4 a = *(const float4*)f;
    float4 b = *(const float4*)(f + 4);
    o[0] = (_Float16)a.x; o[1] = (_Float16)a.y;
    o[2] = (_Float16)a.z; o[3] = (_Float16)a.w;
    o[4] = (_Float16)b.x; o[5] = (_Float16)b.y;
    o[6] = (_Float16)b.z; o[7] = (_Float16)b.w;
  }
  *(h8*)dst = o;
}

// Load 8 strided elements (transposed staging) -> 8 fp16 into LDS.
DEV void stage8t(const void* src, int isbf, size_t base, size_t stride, _Float16* dst) {
  h8 o;
#pragma unroll
  for (int j = 0; j < 8; ++j) o[j] = (_Float16)load_elem(src, isbf, base + (size_t)j * stride);
  *(h8*)dst = o;
}

// ---------- K0: seed outputs (mean=bo, var=0) and zero rs ----------
__global__ __launch_bounds__(256) void zero_seed(float* __restrict__ om,
                                                 float* __restrict__ ov,
                                                 float* __restrict__ rs,
                                                 const void* bo, const void* xdet) {
  int isbf = detect_bf16(xdet);
  size_t idx = (size_t)blockIdx.x * 256 + threadIdx.x;  // float4 units
  size_t i = idx * 4;
  if (idx < 524288) {  // out_mean: 2097152 floats
    int c0 = (int)(i & 255);
    float4 v = {load_elem(bo, isbf, c0), load_elem(bo, isbf, c0 + 1),
                load_elem(bo, isbf, c0 + 2), load_elem(bo, isbf, c0 + 3)};
    *(float4*)(om + i) = v;
  } else {
    float4 z = {0.f, 0.f, 0.f, 0.f};
    *(float4*)(ov + (i - 2097152)) = z;
  }
  if (blockIdx.x < 32) rs[blockIdx.x * 256 + threadIdx.x] = 0.f;
}

// ---------- K0b: M = Wo@Wv (fp32, row-major), c = Wo@bv ----------
// grid (2,2): 128x128 tiles. B staged transposed (Wv^T) via strided scalar loads.
__global__ __launch_bounds__(256) void prep_kernel(const void* Wo, const void* Wv,
                                                   const void* bv, const void* xdet,
                                                   float* __restrict__ M,
                                                   float* __restrict__ c) {
  __shared__ __align__(16) _Float16 As[4096];
  __shared__ __align__(16) _Float16 Bs[4096];
  int isbf = detect_bf16(xdet);
  const int t = threadIdx.x;
  const int lane = t & 63, wave = t >> 6;
  const int wr = wave >> 1, wc = wave & 1;
  const int q = lane >> 4, m = lane & 15;
  const size_t i0 = (size_t)blockIdx.x * 128, j0 = (size_t)blockIdx.y * 128;
  if (blockIdx.x == 0 && blockIdx.y == 0) {  // c = Wo @ bv
    float s = 0.f;
    for (int j = 0; j < 256; ++j) s += load_elem(Wo, isbf, (size_t)t * 256 + j) * load_elem(bv, isbf, j);
    c[t] = s;
  }
  floatx4 acc[4][4] = {};
  for (int k0 = 0; k0 < 256; k0 += 32) {
#pragma unroll
    for (int it = 0; it < 2; ++it) {
      int e = it * 2048 + t * 8;
      int row = e >> 5, col = e & 31;
      stage8h(Wo, isbf, (i0 + row) * (size_t)256 + k0 + col, &As[e]);
      // Bs[row][col..] = Wv^T[j0+row][k0+col..] = Wv[(k0+col..)*256 + j0+row]
      stage8t(Wv, isbf, (size_t)(k0 + col) * 256 + (j0 + row), 256, &Bs[e]);
    }
    __syncthreads();
    h8 af[4], bfr[4];
#pragma unroll
    for (int r = 0; r < 4; ++r)
      af[r] = *(const h8*)&As[(wr * 64 + r * 16 + m) * 32 + q * 8];
#pragma unroll
    for (int cc = 0; cc < 4; ++cc)
      bfr[cc] = *(const h8*)&Bs[(wc * 64 + cc * 16 + m) * 32 + q * 8];
#pragma unroll
    for (int r = 0; r < 4; ++r)
#pragma unroll
      for (int cc = 0; cc < 4; ++cc)
        acc[r][cc] = __builtin_amdgcn_mfma_f32_16x16x32_f16(af[r], bfr[cc], acc[r][cc], 0, 0, 0);
    __syncthreads();
  }
#pragma unroll
  for (int r = 0; r < 4; ++r)
#pragma unroll
    for (int cc = 0; cc < 4; ++cc) {
      size_t col = j0 + wc * 64 + cc * 16 + m;
#pragma unroll
      for (int g = 0; g < 4; ++g) {
        size_t row = i0 + wr * 64 + r * 16 + q * 4 + g;
        M[row * 256 + col] = acc[r][cc][g];
      }
    }
}

// ---------- K1: four projections -> fp16 fragment-linear (LDS-transpose epilogue) ----------
struct ProjArgs {
  const void* A[4];
  const void* B[4];
  const void* bias[4];
  _Float16* C[4];
  int fl_tpc[4];
  float scale[4];
  int bias_row[4];
  int a_f32[4];     // force A fp32 (ws-resident M)
  int bias_f32[4];  // force bias fp32 (ws-resident c)
  const void* xdet;
};

__global__ __launch_bounds__(256) void proj_kernel(ProjArgs p) {
  __shared__ __align__(16) char smem[34816];
  _Float16* As = (_Float16*)smem;
  _Float16* Bs = As + 4096;
  _Float16* Ts = (_Float16*)smem;
  int isbf = detect_bf16(p.xdet);
  int z = blockIdx.z;
  size_t i0, j0;
  if (z < 2) { i0 = (size_t)blockIdx.x * 128; j0 = (size_t)blockIdx.y * 128; }
  else       { i0 = (size_t)blockIdx.y * 128; j0 = (size_t)blockIdx.x * 128; }
  const void* A = p.A[z];
  const void* B = p.B[z];
  const void* bias = p.bias[z];
  const float scale = p.scale[z];
  const int bias_row = p.bias_row[z];
  const int tpc = p.fl_tpc[z];
  const int a_bf = p.a_f32[z] ? 0 : isbf;
  const int bias_bf = p.bias_f32[z] ? 0 : isbf;
  _Float16* C = p.C[z];
  const int t = threadIdx.x;
  const int lane = t & 63, wave = t >> 6;
  const int wr = wave >> 1, wc = wave & 1;
  const int q = lane >> 4, m = lane & 15;
  floatx4 acc[4][4] = {};
  for (int k0 = 0; k0 < 256; k0 += 32) {
#pragma unroll
    for (int it = 0; it < 2; ++it) {
      int e = it * 2048 + t * 8;
      int row = e >> 5, col = e & 31;
      stage8h(A, a_bf, (i0 + row) * (size_t)256 + k0 + col, &As[e]);
      stage8h(B, isbf, (j0 + row) * (size_t)256 + k0 + col, &Bs[e]);
    }
    __syncthreads();
    h8 af[4], bfr[4];
#pragma unroll
    for (int r = 0; r < 4; ++r)
      af[r] = *(const h8*)&As[(wr * 64 + r * 16 + m) * 32 + q * 8];
#pragma unroll
    for (int c = 0; c < 4; ++c)
      bfr[c] = *(const h8*)&Bs[(wc * 64 + c * 16 + m) * 32 + q * 8];
#pragma unroll
    for (int r = 0; r < 4; ++r)
#pragma unroll
      for (int c = 0; c < 4; ++c)
        acc[r][c] = __builtin_amdgcn_mfma_f32_16x16x32_f16(af[r], bfr[c], acc[r][c], 0, 0, 0);
    __syncthreads();
  }
#pragma unroll
  for (int r = 0; r < 4; ++r)
#pragma unroll
    for (int c = 0; c < 4; ++c) {
      size_t col = j0 + wc * 64 + c * 16 + m;
      float bcol = bias_row ? 0.f : load_elem(bias, bias_bf, col);
#pragma unroll
      for (int g = 0; g < 4; ++g) {
        size_t row = i0 + wr * 64 + r * 16 + q * 4 + g;
        float val = acc[r][c][g] + bcol;
        if (bias_row) val += load_elem(bias, bias_bf, row);
        Ts[(wr * 64 + r * 16 + q * 4 + g) * 136 + wc * 64 + c * 16 + m] =
            (_Float16)(val * scale);
      }
    }
  __syncthreads();
  size_t ti0 = i0 >> 4, tj0 = j0 >> 5;
#pragma unroll
  for (int it = 0; it < 8; ++it) {
    int cch = it * 4 + wave;
    int ci = cch >> 2, ck = cch & 3;
    int il = ci * 16 + (lane & 15);
    int jl = ck * 32 + (lane >> 4) * 8;
    h8 v = *(const h8*)&Ts[il * 136 + jl];
    *(h8*)&C[((ti0 + ci) * (size_t)tpc + (tj0 + ck)) * 512 + lane * 8] = v;
  }
}

// ---------- K2: E = exp(q'@k^T)*2^-6, fragment-linear out + row sums ----------
// (proven R8/R11 version, untouched)
__global__ __launch_bounds__(256) void qk_exp_kernel(const _Float16* __restrict__ qb,
                                                     const _Float16* __restrict__ kb,
                                                     _Float16* __restrict__ E,
                                                     float* __restrict__ rs) {
  __shared__ __align__(16) char smem[128 * 136 * 2];
  _Float16* As = (_Float16*)smem;
  _Float16* Bs = As + 4096;
  _Float16* Ts = (_Float16*)smem;
  const int t = threadIdx.x;
  const int lane = t & 63, wave = t >> 6;
  const int wr = wave >> 1, wc = wave & 1;
  const int q = lane >> 4, m = lane & 15;
  const size_t bx = blockIdx.x, by = blockIdx.y;
  const size_t i0 = bx * 128;
  floatx4 acc[4][4] = {};
  for (int kt = 0; kt < 8; ++kt) {
#pragma unroll
    for (int it = 0; it < 2; ++it) {
      int c = it * 4 + wave;
      async_ld16(&qb[((bx * 8 + c) * 8 + kt) * 512 + lane * 8], &As[c * 512 + lane * 8]);
      async_ld16(&kb[((by * 8 + c) * 8 + kt) * 512 + lane * 8], &Bs[c * 512 + lane * 8]);
    }
    __syncthreads();
    h8 af[4], bfr[4];
#pragma unroll
    for (int r = 0; r < 4; ++r)
      af[r] = *(const h8*)&As[(wr * 4 + r) * 512 + lane * 8];
#pragma unroll
    for (int c = 0; c < 4; ++c)
      bfr[c] = *(const h8*)&Bs[(wc * 4 + c) * 512 + lane * 8];
#pragma unroll
    for (int r = 0; r < 4; ++r)
#pragma unroll
      for (int c = 0; c < 4; ++c)
        acc[r][c] = __builtin_amdgcn_mfma_f32_16x16x32_f16(af[r], bfr[c], acc[r][c], 0, 0, 0);
    __syncthreads();
  }
#pragma unroll
  for (int r = 0; r < 4; ++r)
#pragma unroll
    for (int c = 0; c < 4; ++c)
#pragma unroll
      for (int g = 0; g < 4; ++g)
        acc[r][c][g] = __expf(fminf(acc[r][c][g], 8.f)) * 0.015625f;
#pragma unroll
  for (int r = 0; r < 4; ++r)
#pragma unroll
    for (int g = 0; g < 4; ++g) {
      float part = acc[r][0][g] + acc[r][1][g] + acc[r][2][g] + acc[r][3][g];
      part += __shfl_xor(part, 1);
      part += __shfl_xor(part, 2);
      part += __shfl_xor(part, 4);
      part += __shfl_xor(part, 8);
      if (m == 0)
        unsafeAtomicAdd(&rs[i0 + wr * 64 + r * 16 + q * 4 + g], part);
    }
#pragma unroll
  for (int r = 0; r < 4; ++r)
#pragma unroll
    for (int c = 0; c < 4; ++c)
#pragma unroll
      for (int g = 0; g < 4; ++g)
        Ts[(wr * 64 + r * 16 + q * 4 + g) * 136 + wc * 64 + c * 16 + m] =
            (_Float16)acc[r][c][g];
  __syncthreads();
#pragma unroll
  for (int it = 0; it < 8; ++it) {
    int cch = it * 4 + wave;
    int ci = cch >> 2, ck = cch & 3;
    int il = ci * 16 + (lane & 15);
    int jl = ck * 32 + (lane >> 4) * 8;
    h8 v = *(const h8*)&Ts[il * 136 + jl];
    *(h8*)&E[((bx * 8 + ci) * 256 + by * 4 + ck) * 512 + lane * 8] = v;
  }
}

// ---------- K3: out_mean += (E@u^T)/rs, out_var += (E^2@vv^T)/rs^2 ----------
// A-operand direct global->VGPR (fragment-linear, coalesced 1KB/wave); B via LDS.
// BM=64, BN=128, BK=32. grid (128,2,4) = 1024 blocks = 4/CU at 16 KB LDS,
// matching launch_bounds(256,4)'s 4 waves/SIMD.
__global__ __launch_bounds__(256, 4) void av_fused(const _Float16* __restrict__ E,
                                                   const _Float16* __restrict__ uT,
                                                   const _Float16* __restrict__ vvT,
                                                   const float* __restrict__ rs,
                                                   float* __restrict__ om,
                                                   float* __restrict__ ov) {
  __shared__ __align__(16) _Float16 B1s[8 * 512];   // 8 KB
  __shared__ __align__(16) _Float16 B2s[8 * 512];   // 8 KB
  const int t = threadIdx.x;
  const int lane = t & 63, wave = t >> 6;
  const int wr = wave >> 1, wc = wave & 1;
  const int q = lane >> 4, m = lane & 15;
  const size_t bx = blockIdx.x, by = blockIdx.y;
  const int kt0 = blockIdx.z * 64;
  size_t boff0 = ((by * 8 + (size_t)wave) * 256 + (size_t)kt0) * 512 + lane * 8;
  size_t boff1 = ((by * 8 + (size_t)wave + 4) * 256 + (size_t)kt0) * 512 + lane * 8;
  const _Float16* ap0 = E + ((bx * 4 + (size_t)(wr * 2 + 0)) * 256 + (size_t)kt0) * 512 + lane * 8;
  const _Float16* ap1 = E + ((bx * 4 + (size_t)(wr * 2 + 1)) * 256 + (size_t)kt0) * 512 + lane * 8;
  floatx4 accm[2][4] = {}, accv[2][4] = {};
  for (int kk = 0; kk < 64; ++kk) {
    async_ld16(&uT[boff0], &B1s[wave * 512 + lane * 8]);
    async_ld16(&uT[boff1], &B1s[(wave + 4) * 512 + lane * 8]);
    async_ld16(&vvT[boff0], &B2s[wave * 512 + lane * 8]);
    async_ld16(&vvT[boff1], &B2s[(wave + 4) * 512 + lane * 8]);
    h8 a0 = *(const h8*)ap0;
    h8 a1 = *(const h8*)ap1;
    __syncthreads();
    h8 a0q = a0 * a0, a1q = a1 * a1;  // v_pk_mul_f16
#pragma unroll
    for (int c = 0; c < 4; ++c) {
      h8 b1 = *(const h8*)&B1s[(wc * 4 + c) * 512 + lane * 8];
      h8 b2 = *(const h8*)&B2s[(wc * 4 + c) * 512 + lane * 8];
      accm[0][c] = __builtin_amdgcn_mfma_f32_16x16x32_f16(a0, b1, accm[0][c], 0, 0, 0);
      accm[1][c] = __builtin_amdgcn_mfma_f32_16x16x32_f16(a1, b1, accm[1][c], 0, 0, 0);
      accv[0][c] = __builtin_amdgcn_mfma_f32_16x16x32_f16(a0q, b2, accv[0][c], 0, 0, 0);
      accv[1][c] = __builtin_amdgcn_mfma_f32_16x16x32_f16(a1q, b2, accv[1][c], 0, 0, 0);
    }
    __syncthreads();
    ap0 += 512; ap1 += 512; boff0 += 512; boff1 += 512;
  }
#pragma unroll
  for (int r = 0; r < 2; ++r)
#pragma unroll
    for (int g = 0; g < 4; ++g) {
      size_t row = bx * 64 + wr * 32 + r * 16 + q * 4 + g;
      float inv = 1.f / rs[row];
      float inv2 = inv * inv;
#pragma unroll
      for (int c = 0; c < 4; ++c) {
        size_t col = by * 128 + wc * 64 + c * 16 + m;
        unsafeAtomicAdd(&om[row * 256 + col], accm[r][c][g] * inv);
        unsafeAtomicAdd(&ov[row * 256 + col], accv[r][c][g] * inv2);
      }
    }
}

extern "C" void kernel_launch(void* const* d_in, const int* in_sizes, int n_in,
                              void* d_out, int out_size, void* d_ws, size_t ws_size,
                              hipStream_t stream) {
  const void* x_mean = d_in[0];
  const void* x_var  = d_in[1];
  // d_in[2] edge_index, d_in[3] edge_timestamps: unused by the reference
  const void* Wq   = d_in[4];
  const void* bq   = d_in[5];
  const void* Wk   = d_in[6];
  const void* bk   = d_in[7];
  const void* Wv   = d_in[8];
  const void* bv   = d_in[9];
  const void* Wo   = d_in[10];
  const void* bo   = d_in[11];
  const void* Wvar = d_in[12];
  const void* bvar = d_in[13];
  float* out = (float*)d_out;  // [out_mean (8192*256) | out_var (8192*256)] fp32

  const size_t NE_S = 67108864;  // 8192*8192
  const size_t NE_P = 2097152;   // 8192*256
  if (ws_size < (NE_S + 5 * NE_P) * 2) return;  // ~155 MB scratch
  _Float16* w   = (_Float16*)d_ws;
  _Float16* S   = w;              // E = exp(logits)*2^-6, fragment-linear [8192x8192]
  _Float16* qb  = w + NE_S;       // q*0.125 (+bq), fragment-linear [8192x256]
  _Float16* kb  = qb + NE_P;      // k, fragment-linear [8192x256]
  _Float16* uT  = kb + NE_P;      // (v@Wo^T)^T, fragment-linear [256x8192]
  _Float16* vvT = uT + NE_P;      // v_var^T, fragment-linear [256x8192]
  float* rs     = (float*)(vvT + NE_P);  // row sums of E [8192]
  float* M      = rs + 8192;             // Wo@Wv fp32 [256x256]
  float* c      = M + 65536;             // Wo@bv fp32 [256]

  ProjArgs p;
  p.A[0] = x_mean; p.B[0] = Wq;     p.bias[0] = bq;   p.C[0] = qb;  p.fl_tpc[0] = 8;   p.scale[0] = 0.125f; p.bias_row[0] = 0; p.a_f32[0] = 0; p.bias_f32[0] = 0;
  p.A[1] = x_mean; p.B[1] = Wk;     p.bias[1] = bk;   p.C[1] = kb;  p.fl_tpc[1] = 8;   p.scale[1] = 1.f;    p.bias_row[1] = 0; p.a_f32[1] = 0; p.bias_f32[1] = 0;
  p.A[2] = M;      p.B[2] = x_mean; p.bias[2] = c;    p.C[2] = uT;  p.fl_tpc[2] = 256; p.scale[2] = 1.f;    p.bias_row[2] = 1; p.a_f32[2] = 1; p.bias_f32[2] = 1;
  p.A[3] = Wvar;   p.B[3] = x_var;  p.bias[3] = bvar; p.C[3] = vvT; p.fl_tpc[3] = 256; p.scale[3] = 1.f;    p.bias_row[3] = 1; p.a_f32[3] = 0; p.bias_f32[3] = 0;
  p.xdet = x_mean;

  zero_seed<<<dim3(4096), 256, 0, stream>>>(out, out + NE_P, rs, bo, x_mean);
  prep_kernel<<<dim3(2, 2), 256, 0, stream>>>(Wo, Wv, bv, x_mean, M, c);
  proj_kernel<<<dim3(64, 2, 4), 256, 0, stream>>>(p);
  qk_exp_kernel<<<dim3(64, 64), 256, 0, stream>>>(qb, kb, S, rs);
  av_fused<<<dim3(128, 2, 4), 256, 0, stream>>>(S, uT, vvT, rs, out, out + NE_P);
}